// Round 1
// baseline (378.097 us; speedup 1.0000x reference)
//
#include <hip/hip_runtime.h>
#include <math.h>

#define BB   4
#define MM   1024
#define NN   1024
#define DD   9
#define KSEL 16
#define NROW (BB * MM)

// Workspace layout (doubles first for 8B alignment). Harness poisons ws with
// 0xAA before every launch; stats_kernel rewrites everything used downstream.
struct Ws {
  double intra_sum;
  double outer_sum;
  float  cnt;
  float  mean[DD];
  float  cinv[DD * DD];
  float  qy[BB * NN];
};

// ---------------------------------------------------------------------------
// Kernel 1: single block. cnt, mean, cov (raw-moment form), 9x9 inverse (fp64
// Gauss-Jordan w/ partial pivoting == pinv for this well-conditioned cov),
// and zero the loss accumulators.
// ---------------------------------------------------------------------------
__global__ __launch_bounds__(256) void stats_kernel(
    const float* __restrict__ targets, const int* __restrict__ mask,
    Ws* __restrict__ ws) {
  const int tid = threadIdx.x;
  float acc[55];  // [0]=cnt, [1..9]=sum t, [10..54]=upper-tri sum t_p t_q
#pragma unroll
  for (int k = 0; k < 55; ++k) acc[k] = 0.f;

  for (int r = tid; r < NROW; r += 256) {
    if (mask[r] != 0) {
      float t[DD];
#pragma unroll
      for (int k = 0; k < DD; ++k) t[k] = targets[r * DD + k];
      acc[0] += 1.f;
#pragma unroll
      for (int k = 0; k < DD; ++k) acc[1 + k] += t[k];
      int u = 10;
#pragma unroll
      for (int p = 0; p < DD; ++p)
#pragma unroll
        for (int q = p; q < DD; ++q) acc[u++] += t[p] * t[q];
    }
  }

  __shared__ float lds[4][55];
#pragma unroll
  for (int k = 0; k < 55; ++k) {
    float v = acc[k];
#pragma unroll
    for (int off = 32; off > 0; off >>= 1) v += __shfl_down(v, off, 64);
    if ((tid & 63) == 0) lds[tid >> 6][k] = v;
  }
  __syncthreads();

  if (tid == 0) {
    double S[55];
    for (int k = 0; k < 55; ++k)
      S[k] = (double)lds[0][k] + (double)lds[1][k] + (double)lds[2][k] +
             (double)lds[3][k];
    const double cnt = S[0];
    double mean[DD];
    for (int k = 0; k < DD; ++k) mean[k] = S[1 + k] / cnt;

    // cov = (S_pq - cnt*mu_p*mu_q)/(cnt-1); augmented [cov | I]
    double A[DD][2 * DD];
    {
      int u = 10;
      for (int p = 0; p < DD; ++p)
        for (int q = p; q < DD; ++q) {
          double c = (S[u++] - cnt * mean[p] * mean[q]) / (cnt - 1.0);
          A[p][q] = c;
          A[q][p] = c;
        }
    }
    for (int p = 0; p < DD; ++p)
      for (int q = 0; q < DD; ++q) A[p][DD + q] = (p == q) ? 1.0 : 0.0;

    for (int col = 0; col < DD; ++col) {
      int piv = col;
      double best = fabs(A[col][col]);
      for (int r2 = col + 1; r2 < DD; ++r2) {
        double m2 = fabs(A[r2][col]);
        if (m2 > best) { best = m2; piv = r2; }
      }
      if (piv != col)
        for (int q = 0; q < 2 * DD; ++q) {
          double tmp = A[col][q]; A[col][q] = A[piv][q]; A[piv][q] = tmp;
        }
      double inv = 1.0 / A[col][col];
      for (int q = 0; q < 2 * DD; ++q) A[col][q] *= inv;
      for (int r2 = 0; r2 < DD; ++r2)
        if (r2 != col) {
          double f = A[r2][col];
          if (f != 0.0)
            for (int q = 0; q < 2 * DD; ++q) A[r2][q] -= f * A[col][q];
        }
    }

    ws->cnt = (float)cnt;
    for (int k = 0; k < DD; ++k) ws->mean[k] = (float)mean[k];
    for (int p = 0; p < DD; ++p)
      for (int q = 0; q < DD; ++q) ws->cinv[p * DD + q] = (float)A[p][DD + q];
    ws->intra_sum = 0.0;
    ws->outer_sum = 0.0;
  }
}

// ---------------------------------------------------------------------------
// Kernel 2: qy[j] = y_j^T Cinv y_j for every y_pred row (shared by both
// distance phases).
// ---------------------------------------------------------------------------
__global__ __launch_bounds__(256) void qy_kernel(
    const float* __restrict__ outputs, Ws* __restrict__ ws) {
  const int j = blockIdx.x * 256 + threadIdx.x;  // < BB*NN
  float C[DD * DD];
#pragma unroll
  for (int k = 0; k < DD * DD; ++k) C[k] = ws->cinv[k];
  float y[DD];
#pragma unroll
  for (int k = 0; k < DD; ++k) y[k] = outputs[j * DD + k];
  float q = 0.f;
#pragma unroll
  for (int p = 0; p < DD; ++p) {
    float s = 0.f;
#pragma unroll
    for (int t = 0; t < DD; ++t) s += C[p * DD + t] * y[t];
    q += y[p] * s;
  }
  ws->qy[j] = q;
}

// ---------------------------------------------------------------------------
// Kernel 3: one block per row. d_j = qa + qy_j - 2*dot(w, y_j); sum of the 16
// smallest over j (iterated block argmin); double atomic into the loss sum.
// INTRA: a = t_i - mean, masked rows skipped. OUTER: a = y_i + mean
// (xc = y_j - y_i - mean = y_j - a; quadratic form is sign-invariant).
// ---------------------------------------------------------------------------
template <bool INTRA>
__global__ __launch_bounds__(256) void dist_topk_kernel(
    const float* __restrict__ outputs, const float* __restrict__ targets,
    const int* __restrict__ mask, Ws* __restrict__ ws) {
  const int r = blockIdx.x;  // row id in [0, BB*MM)
  const int b = r >> 10;
  const int tid = threadIdx.x;

  if (INTRA) {
    if (mask[r] == 0) return;  // block-uniform early exit
  }

  float mean[DD], C[DD * DD];
#pragma unroll
  for (int k = 0; k < DD; ++k) mean[k] = ws->mean[k];
#pragma unroll
  for (int k = 0; k < DD * DD; ++k) C[k] = ws->cinv[k];

  float a[DD];
  if (INTRA) {
#pragma unroll
    for (int k = 0; k < DD; ++k) a[k] = targets[r * DD + k] - mean[k];
  } else {
#pragma unroll
    for (int k = 0; k < DD; ++k) a[k] = outputs[r * DD + k] + mean[k];
  }
  float w[DD];
  float qa = 0.f;
#pragma unroll
  for (int p = 0; p < DD; ++p) {
    float s = 0.f;
#pragma unroll
    for (int t = 0; t < DD; ++t) s += C[p * DD + t] * a[t];
    w[p] = s;
    qa += a[p] * s;
  }

  const float* __restrict__ yb = outputs + (size_t)b * NN * DD;
  const float* __restrict__ qyb = ws->qy + b * NN;

  float v[4];
#pragma unroll
  for (int k = 0; k < 4; ++k) {
    const int j = tid + k * 256;
    float dot = 0.f;
#pragma unroll
    for (int p = 0; p < DD; ++p) dot += w[p] * yb[j * DD + p];
    v[k] = qa + qyb[j] - 2.f * dot;
  }

  __shared__ float s_val[4];
  __shared__ int s_idx[4];
  __shared__ int s_win_j;
  float total = 0.f;  // thread 0 only

  for (int round = 0; round < KSEL; ++round) {
    float bv = v[0];
    int bj = tid;
#pragma unroll
    for (int k = 1; k < 4; ++k)
      if (v[k] < bv) { bv = v[k]; bj = tid + k * 256; }
#pragma unroll
    for (int off = 32; off > 0; off >>= 1) {
      float ov = __shfl_down(bv, off, 64);
      int oj = __shfl_down(bj, off, 64);
      if (ov < bv) { bv = ov; bj = oj; }
    }
    if ((tid & 63) == 0) { s_val[tid >> 6] = bv; s_idx[tid >> 6] = bj; }
    __syncthreads();
    if (tid == 0) {
      float wv = s_val[0];
      int wj = s_idx[0];
#pragma unroll
      for (int q = 1; q < 4; ++q)
        if (s_val[q] < wv) { wv = s_val[q]; wj = s_idx[q]; }
      total += wv;
      s_win_j = wj;
    }
    __syncthreads();
    const int wj = s_win_j;
#pragma unroll
    for (int k = 0; k < 4; ++k)
      if (wj == tid + k * 256) v[k] = __builtin_huge_valf();
  }

  if (tid == 0) {
    atomicAdd(INTRA ? &ws->intra_sum : &ws->outer_sum, (double)total);
  }
}

// ---------------------------------------------------------------------------
// Kernel 4: finalize the three scalars.
// ---------------------------------------------------------------------------
__global__ void finalize_kernel(const Ws* __restrict__ ws,
                                float* __restrict__ out) {
  const double cnt = (double)ws->cnt;
  const float intra = (float)(ws->intra_sum / cnt);
  const float outer =
      (float)(ws->outer_sum / (double)((long long)BB * NN * KSEL));
  out[0] = intra;
  out[1] = intra;
  out[2] = outer;
}

extern "C" void kernel_launch(void* const* d_in, const int* in_sizes, int n_in,
                              void* d_out, int out_size, void* d_ws,
                              size_t ws_size, hipStream_t stream) {
  const float* outputs = (const float*)d_in[0];  // (4,1024,9) f32
  const float* targets = (const float*)d_in[1];  // (4,1024,9) f32
  const int* mask = (const int*)d_in[2];         // (4,1024) bool->int
  Ws* ws = (Ws*)d_ws;
  float* out = (float*)d_out;

  stats_kernel<<<1, 256, 0, stream>>>(targets, mask, ws);
  qy_kernel<<<(BB * NN) / 256, 256, 0, stream>>>(outputs, ws);
  dist_topk_kernel<true><<<NROW, 256, 0, stream>>>(outputs, targets, mask, ws);
  dist_topk_kernel<false><<<BB * NN, 256, 0, stream>>>(outputs, targets, mask,
                                                       ws);
  finalize_kernel<<<1, 1, 0, stream>>>(ws, out);
}

// Round 2
// 192.231 us; speedup vs baseline: 1.9669x; 1.9669x over previous
//
#include <hip/hip_runtime.h>
#include <math.h>

#define BB   4
#define MM   1024
#define NN   1024
#define DD   9
#define KSEL 16
#define NROW (BB * MM)

// Workspace. Harness poisons with 0xAA before every launch; kernel_launch
// memsets S/intra/outer to zero, stats_reduce+invert rewrite the rest.
struct Ws {
  double S[55];       // [0]=cnt, [1..9]=sum t, [10..54]=upper-tri sum t_p t_q
  double intra_sum;
  double outer_sum;
  float  cnt;
  float  mean[DD];
  float  cinv[DD * DD];
  float  qy[BB * NN];
};

// ---------------------------------------------------------------------------
// Kernel 1: 16 blocks x 256 threads, one target row per thread. 55 partial
// sums -> shuffle reduce -> LDS across 4 waves -> one fp64 atomic per value
// per block. (Round-1 version was a single block + thread-0 fp64 Gauss-Jordan
// with runtime-indexed arrays -> scratch spills -> 215 us. This is the fix.)
// ---------------------------------------------------------------------------
__global__ __launch_bounds__(256) void stats_reduce(
    const float* __restrict__ targets, const int* __restrict__ mask,
    Ws* __restrict__ ws) {
  const int tid = threadIdx.x;
  const int r = blockIdx.x * 256 + tid;  // exactly covers NROW=4096 with 16 blocks

  float acc[55];
#pragma unroll
  for (int k = 0; k < 55; ++k) acc[k] = 0.f;

  if (mask[r] != 0) {
    float t[DD];
#pragma unroll
    for (int k = 0; k < DD; ++k) t[k] = targets[r * DD + k];
    acc[0] = 1.f;
#pragma unroll
    for (int k = 0; k < DD; ++k) acc[1 + k] = t[k];
    int u = 10;
#pragma unroll
    for (int p = 0; p < DD; ++p)
#pragma unroll
      for (int q = p; q < DD; ++q) acc[u++] = t[p] * t[q];
  }

  __shared__ float lds[4][55];
#pragma unroll
  for (int k = 0; k < 55; ++k) {
    float v = acc[k];
#pragma unroll
    for (int off = 32; off > 0; off >>= 1) v += __shfl_down(v, off, 64);
    if ((tid & 63) == 0) lds[tid >> 6][k] = v;
  }
  __syncthreads();

  if (tid < 55) {
    double v = (double)lds[0][tid] + (double)lds[1][tid] +
               (double)lds[2][tid] + (double)lds[3][tid];
    atomicAdd(&ws->S[tid], v);
  }
}

// ---------------------------------------------------------------------------
// Kernel 2: one wave. Lane p (p<9) owns row p of the augmented [cov | I].
// All loops fully unrolled => static register indexing (no scratch).
// Gauss-Jordan WITHOUT pivoting: cov of ~2048 N(0,1) 9-dim samples is SPD,
// diag ~= 1, condition ~1.2 -> pivoting unnecessary, pinv == inverse.
// ---------------------------------------------------------------------------
__global__ __launch_bounds__(64) void invert_kernel(Ws* __restrict__ ws) {
  const int lane = threadIdx.x;
  const double cnt = ws->S[0];

  double row[2 * DD];
  const int p = (lane < DD) ? lane : 0;  // junk lanes mirror row 0 (discarded)
  {
    const double mu_p = ws->S[1 + p] / cnt;
#pragma unroll
    for (int q = 0; q < DD; ++q) {
      const int pp = (p < q) ? p : q;
      const int qq = (p < q) ? q : p;
      const int idx = 10 + 9 * pp - (pp * (pp - 1)) / 2 + (qq - pp);
      const double mu_q = ws->S[1 + q] / cnt;
      row[q] = (ws->S[idx] - cnt * mu_p * mu_q) / (cnt - 1.0);
      row[DD + q] = (p == q) ? 1.0 : 0.0;
    }
  }

#pragma unroll
  for (int c = 0; c < DD; ++c) {
    const double diag = __shfl(row[c], c, 64);
    const double dinv = 1.0 / diag;
    if (lane == c) {
#pragma unroll
      for (int q = 0; q < 2 * DD; ++q) row[q] *= dinv;
    }
    const double f = (lane == c) ? 0.0 : row[c];
#pragma unroll
    for (int q = 0; q < 2 * DD; ++q) {
      const double pv = __shfl(row[q], c, 64);
      row[q] -= f * pv;
    }
  }

  if (lane < DD) {
#pragma unroll
    for (int q = 0; q < DD; ++q)
      ws->cinv[lane * DD + q] = (float)row[DD + q];
  }
  if (lane == 0) {
    ws->cnt = (float)cnt;
#pragma unroll
    for (int q = 0; q < DD; ++q) ws->mean[q] = (float)(ws->S[1 + q] / cnt);
  }
}

// ---------------------------------------------------------------------------
// Kernel 3: qy[j] = y_j^T Cinv y_j (shared by both distance phases).
// ---------------------------------------------------------------------------
__global__ __launch_bounds__(256) void qy_kernel(
    const float* __restrict__ outputs, Ws* __restrict__ ws) {
  const int j = blockIdx.x * 256 + threadIdx.x;  // < BB*NN
  float C[DD * DD];
#pragma unroll
  for (int k = 0; k < DD * DD; ++k) C[k] = ws->cinv[k];
  float y[DD];
#pragma unroll
  for (int k = 0; k < DD; ++k) y[k] = outputs[j * DD + k];
  float q = 0.f;
#pragma unroll
  for (int p = 0; p < DD; ++p) {
    float s = 0.f;
#pragma unroll
    for (int t = 0; t < DD; ++t) s += C[p * DD + t] * y[t];
    q += y[p] * s;
  }
  ws->qy[j] = q;
}

// ---------------------------------------------------------------------------
// Kernel 4: one block per row. d_j = qa + qy_j - 2*dot(w, y_j); sum of the 16
// smallest over j (iterated block argmin); double atomic into the loss sum.
// INTRA: a = t_i - mean, masked rows skipped. OUTER: a = y_i + mean
// (xc = y_j - y_i - mean = y_j - a; quadratic form is sign-invariant).
// ---------------------------------------------------------------------------
template <bool INTRA>
__global__ __launch_bounds__(256) void dist_topk_kernel(
    const float* __restrict__ outputs, const float* __restrict__ targets,
    const int* __restrict__ mask, Ws* __restrict__ ws) {
  const int r = blockIdx.x;  // row id in [0, BB*MM)
  const int b = r >> 10;
  const int tid = threadIdx.x;

  if (INTRA) {
    if (mask[r] == 0) return;  // block-uniform early exit
  }

  float mean[DD], C[DD * DD];
#pragma unroll
  for (int k = 0; k < DD; ++k) mean[k] = ws->mean[k];
#pragma unroll
  for (int k = 0; k < DD * DD; ++k) C[k] = ws->cinv[k];

  float a[DD];
  if (INTRA) {
#pragma unroll
    for (int k = 0; k < DD; ++k) a[k] = targets[r * DD + k] - mean[k];
  } else {
#pragma unroll
    for (int k = 0; k < DD; ++k) a[k] = outputs[r * DD + k] + mean[k];
  }
  float w[DD];
  float qa = 0.f;
#pragma unroll
  for (int p = 0; p < DD; ++p) {
    float s = 0.f;
#pragma unroll
    for (int t = 0; t < DD; ++t) s += C[p * DD + t] * a[t];
    w[p] = s;
    qa += a[p] * s;
  }

  const float* __restrict__ yb = outputs + (size_t)b * NN * DD;
  const float* __restrict__ qyb = ws->qy + b * NN;

  float v[4];
#pragma unroll
  for (int k = 0; k < 4; ++k) {
    const int j = tid + k * 256;
    float dot = 0.f;
#pragma unroll
    for (int p = 0; p < DD; ++p) dot += w[p] * yb[j * DD + p];
    v[k] = qa + qyb[j] - 2.f * dot;
  }

  __shared__ float s_val[4];
  __shared__ int s_idx[4];
  __shared__ int s_win_j;
  float total = 0.f;  // thread 0 only

  for (int round = 0; round < KSEL; ++round) {
    float bv = v[0];
    int bj = tid;
#pragma unroll
    for (int k = 1; k < 4; ++k)
      if (v[k] < bv) { bv = v[k]; bj = tid + k * 256; }
#pragma unroll
    for (int off = 32; off > 0; off >>= 1) {
      float ov = __shfl_down(bv, off, 64);
      int oj = __shfl_down(bj, off, 64);
      if (ov < bv) { bv = ov; bj = oj; }
    }
    if ((tid & 63) == 0) { s_val[tid >> 6] = bv; s_idx[tid >> 6] = bj; }
    __syncthreads();
    if (tid == 0) {
      float wv = s_val[0];
      int wj = s_idx[0];
#pragma unroll
      for (int q = 1; q < 4; ++q)
        if (s_val[q] < wv) { wv = s_val[q]; wj = s_idx[q]; }
      total += wv;
      s_win_j = wj;
    }
    __syncthreads();
    const int wj = s_win_j;
#pragma unroll
    for (int k = 0; k < 4; ++k)
      if (wj == tid + k * 256) v[k] = __builtin_huge_valf();
  }

  if (tid == 0) {
    atomicAdd(INTRA ? &ws->intra_sum : &ws->outer_sum, (double)total);
  }
}

// ---------------------------------------------------------------------------
// Kernel 5: finalize the three scalars.
// ---------------------------------------------------------------------------
__global__ void finalize_kernel(const Ws* __restrict__ ws,
                                float* __restrict__ out) {
  const double cnt = (double)ws->cnt;
  const float intra = (float)(ws->intra_sum / cnt);
  const float outer =
      (float)(ws->outer_sum / (double)((long long)BB * NN * KSEL));
  out[0] = intra;
  out[1] = intra;
  out[2] = outer;
}

extern "C" void kernel_launch(void* const* d_in, const int* in_sizes, int n_in,
                              void* d_out, int out_size, void* d_ws,
                              size_t ws_size, hipStream_t stream) {
  const float* outputs = (const float*)d_in[0];  // (4,1024,9) f32
  const float* targets = (const float*)d_in[1];  // (4,1024,9) f32
  const int* mask = (const int*)d_in[2];         // (4,1024) bool->int
  Ws* ws = (Ws*)d_ws;
  float* out = (float*)d_out;

  // Zero S[55] + intra_sum + outer_sum (57 doubles) for the atomic reduces.
  hipMemsetAsync(ws, 0, 57 * sizeof(double), stream);

  stats_reduce<<<NROW / 256, 256, 0, stream>>>(targets, mask, ws);
  invert_kernel<<<1, 64, 0, stream>>>(ws);
  qy_kernel<<<(BB * NN) / 256, 256, 0, stream>>>(outputs, ws);
  dist_topk_kernel<true><<<NROW, 256, 0, stream>>>(outputs, targets, mask, ws);
  dist_topk_kernel<false><<<BB * NN, 256, 0, stream>>>(outputs, targets, mask,
                                                       ws);
  finalize_kernel<<<1, 1, 0, stream>>>(ws, out);
}

// Round 3
// 123.242 us; speedup vs baseline: 3.0679x; 1.5598x over previous
//
#include <hip/hip_runtime.h>
#include <math.h>

#define BB   4
#define MM   1024
#define NN   1024
#define DD   9
#define KSEL 16
#define NROW (BB * MM)    // 4096 rows per phase
#define NSLOT (2 * NROW)  // slots 0..4095 intra, 4096..8191 outer

// Workspace. Every field is unconditionally written before it is read
// (per-block partials, per-wave rowsums) => no memset node, no atomics.
struct Ws {
  float part[16][55];    // per-block moment partials: [0]=cnt,[1..9]=sum,[10..54]=tri
  float cnt;
  float mean[DD];
  float cinv[DD * DD];
  float qy[BB * NN];     // y_j^T Cinv y_j
  float rowsum[NSLOT];   // per-row top-16 sum (0 for masked intra rows)
};

// ---------------------------------------------------------------------------
// Kernel 1: 16 blocks x 256, one target row per thread. 55 moment partials ->
// wave shuffle reduce -> LDS across 4 waves -> part[block][k]. No atomics.
// ---------------------------------------------------------------------------
__global__ __launch_bounds__(256) void stats_reduce(
    const float* __restrict__ targets, const int* __restrict__ mask,
    Ws* __restrict__ ws) {
  const int tid = threadIdx.x;
  const int r = blockIdx.x * 256 + tid;

  float acc[55];
#pragma unroll
  for (int k = 0; k < 55; ++k) acc[k] = 0.f;

  if (mask[r] != 0) {
    float t[DD];
#pragma unroll
    for (int k = 0; k < DD; ++k) t[k] = targets[r * DD + k];
    acc[0] = 1.f;
#pragma unroll
    for (int k = 0; k < DD; ++k) acc[1 + k] = t[k];
    int u = 10;
#pragma unroll
    for (int p = 0; p < DD; ++p)
#pragma unroll
      for (int q = p; q < DD; ++q) acc[u++] = t[p] * t[q];
  }

  __shared__ float lds[4][55];
#pragma unroll
  for (int k = 0; k < 55; ++k) {
    float v = acc[k];
#pragma unroll
    for (int off = 32; off > 0; off >>= 1) v += __shfl_down(v, off, 64);
    if ((tid & 63) == 0) lds[tid >> 6][k] = v;
  }
  __syncthreads();

  if (tid < 55)
    ws->part[blockIdx.x][tid] =
        lds[0][tid] + lds[1][tid] + lds[2][tid] + lds[3][tid];
}

// ---------------------------------------------------------------------------
// Kernel 2: one block. (a) sum the 16 moment partials in fp64; (b) wave 0
// does the 9x9 fp64 Gauss-Jordan inverse, lane p owns augmented row p, all
// loops unrolled => register-resident (no pivoting: cov of ~2048 N(0,1)
// samples is SPD, diag~1 => pinv == inverse); (c) all 256 threads compute
// qy[j] for the 4096 y_pred rows using cinv from LDS.
// ---------------------------------------------------------------------------
__global__ __launch_bounds__(256) void prep_kernel(
    const float* __restrict__ outputs, Ws* __restrict__ ws) {
  const int tid = threadIdx.x;
  __shared__ double Sd[55];
  __shared__ float Cs[DD * DD];

  if (tid < 55) {
    double s = 0.0;
#pragma unroll
    for (int b2 = 0; b2 < 16; ++b2) s += (double)ws->part[b2][tid];
    Sd[tid] = s;
  }
  __syncthreads();

  if (tid < 64) {
    const int lane = tid;
    const double cnt = Sd[0];
    const int p = (lane < DD) ? lane : 0;  // junk lanes mirror row 0
    double row[2 * DD];
    {
      const double mu_p = Sd[1 + p] / cnt;
#pragma unroll
      for (int q = 0; q < DD; ++q) {
        const int pp = (p < q) ? p : q;
        const int qq = (p < q) ? q : p;
        const int idx = 10 + 9 * pp - (pp * (pp - 1)) / 2 + (qq - pp);
        const double mu_q = Sd[1 + q] / cnt;
        row[q] = (Sd[idx] - cnt * mu_p * mu_q) / (cnt - 1.0);
        row[DD + q] = (p == q) ? 1.0 : 0.0;
      }
    }
#pragma unroll
    for (int c = 0; c < DD; ++c) {
      const double diag = __shfl(row[c], c, 64);
      const double dinv = 1.0 / diag;
      if (lane == c) {
#pragma unroll
        for (int q = 0; q < 2 * DD; ++q) row[q] *= dinv;
      }
      const double f = (lane == c) ? 0.0 : row[c];
#pragma unroll
      for (int q = 0; q < 2 * DD; ++q) {
        const double pv = __shfl(row[q], c, 64);
        row[q] -= f * pv;
      }
    }
    if (lane < DD) {
#pragma unroll
      for (int q = 0; q < DD; ++q) {
        const float cf = (float)row[DD + q];
        Cs[lane * DD + q] = cf;
        ws->cinv[lane * DD + q] = cf;
      }
    }
    if (lane == 0) {
      ws->cnt = (float)cnt;
#pragma unroll
      for (int q = 0; q < DD; ++q) ws->mean[q] = (float)(Sd[1 + q] / cnt);
    }
  }
  __syncthreads();

  float C[DD * DD];
#pragma unroll
  for (int k = 0; k < DD * DD; ++k) C[k] = Cs[k];
  for (int j = tid; j < BB * NN; j += 256) {
    float y[DD];
#pragma unroll
    for (int k = 0; k < DD; ++k) y[k] = outputs[j * DD + k];
    float q = 0.f;
#pragma unroll
    for (int p = 0; p < DD; ++p) {
      float s = 0.f;
#pragma unroll
      for (int t = 0; t < DD; ++t) s += C[p * DD + t] * y[t];
      q += y[p] * s;
    }
    ws->qy[j] = q;
  }
}

// ---------------------------------------------------------------------------
// Kernel 3: one WAVE per row-slot (4 waves/block, no __syncthreads, no LDS).
// Slot s<4096: intra row s (skip if masked, write 0). s>=4096: outer row
// s-4096. d_j = qa + qy_j - 2*w.y_j; sum of 16 smallest via 16 rounds of
// shuffle min-butterfly + ballot winner + register invalidation.
// ---------------------------------------------------------------------------
__global__ __launch_bounds__(256) void dist_fused(
    const float* __restrict__ outputs, const float* __restrict__ targets,
    const int* __restrict__ mask, Ws* __restrict__ ws) {
  const int s = blockIdx.x * 4 + (threadIdx.x >> 6);
  const int lane = threadIdx.x & 63;
  const bool is_intra = (s < NROW);
  const int r = is_intra ? s : (s - NROW);
  const int b = r >> 10;

  if (is_intra && mask[r] == 0) {
    if (lane == 0) ws->rowsum[s] = 0.f;
    return;
  }

  float mean[DD];
#pragma unroll
  for (int k = 0; k < DD; ++k) mean[k] = ws->mean[k];

  float a[DD];
  if (is_intra) {
#pragma unroll
    for (int k = 0; k < DD; ++k) a[k] = targets[r * DD + k] - mean[k];
  } else {
#pragma unroll
    for (int k = 0; k < DD; ++k) a[k] = outputs[r * DD + k] + mean[k];
  }

  // w = Cinv a, qa = a^T Cinv a. Read cinv from global (L1-hot) row by row
  // to keep peak VGPR low (occupancy: ~8 waves/SIMD).
  float w[DD];
  float qa = 0.f;
#pragma unroll
  for (int p = 0; p < DD; ++p) {
    float acc = 0.f;
#pragma unroll
    for (int t = 0; t < DD; ++t) acc += ws->cinv[p * DD + t] * a[t];
    w[p] = acc;
    qa += a[p] * acc;
  }

  const float* __restrict__ yb = outputs + (size_t)b * NN * DD;
  const float* __restrict__ qyb = ws->qy + b * NN;

  float v[16];
#pragma unroll
  for (int k = 0; k < 16; ++k) {
    const int j = k * 64 + lane;
    float dot = 0.f;
#pragma unroll
    for (int p = 0; p < DD; ++p) dot += w[p] * yb[j * DD + p];
    v[k] = qa + qyb[j] - 2.f * dot;
  }

  float lmin = v[0];
#pragma unroll
  for (int k = 1; k < 16; ++k) lmin = fminf(lmin, v[k]);

  float total = 0.f;
  for (int round = 0; round < KSEL; ++round) {
    float gmin = lmin;
#pragma unroll
    for (int off = 1; off < 64; off <<= 1)
      gmin = fminf(gmin, __shfl_xor(gmin, off, 64));
    total += gmin;  // every lane tracks; lane 0 writes

    const unsigned long long tie = __ballot(lmin == gmin);
    const int winner = __ffsll(tie) - 1;
    if (lane == winner) {
      bool done = false;
#pragma unroll
      for (int k = 0; k < 16; ++k) {
        if (!done && v[k] == gmin) {
          v[k] = __builtin_huge_valf();
          done = true;
        }
      }
      lmin = v[0];
#pragma unroll
      for (int k = 1; k < 16; ++k) lmin = fminf(lmin, v[k]);
    }
  }

  if (lane == 0) ws->rowsum[s] = total;
}

// ---------------------------------------------------------------------------
// Kernel 4: one block; reduce the 8192 row sums into the three scalars.
// ---------------------------------------------------------------------------
__global__ __launch_bounds__(256) void finalize_kernel(
    const Ws* __restrict__ ws, float* __restrict__ out) {
  const int tid = threadIdx.x;
  double li = 0.0, lo = 0.0;
  for (int k = tid; k < NROW; k += 256) {
    li += (double)ws->rowsum[k];
    lo += (double)ws->rowsum[NROW + k];
  }
#pragma unroll
  for (int off = 32; off > 0; off >>= 1) {
    li += __shfl_down(li, off, 64);
    lo += __shfl_down(lo, off, 64);
  }
  __shared__ double lds_i[4], lds_o[4];
  if ((tid & 63) == 0) {
    lds_i[tid >> 6] = li;
    lds_o[tid >> 6] = lo;
  }
  __syncthreads();
  if (tid == 0) {
    const double si = lds_i[0] + lds_i[1] + lds_i[2] + lds_i[3];
    const double so = lds_o[0] + lds_o[1] + lds_o[2] + lds_o[3];
    const double cnt = (double)ws->cnt;
    const float intra = (float)(si / cnt);
    const float outer = (float)(so / (double)(NROW * KSEL));
    out[0] = intra;
    out[1] = intra;
    out[2] = outer;
  }
}

extern "C" void kernel_launch(void* const* d_in, const int* in_sizes, int n_in,
                              void* d_out, int out_size, void* d_ws,
                              size_t ws_size, hipStream_t stream) {
  const float* outputs = (const float*)d_in[0];  // (4,1024,9) f32
  const float* targets = (const float*)d_in[1];  // (4,1024,9) f32
  const int* mask = (const int*)d_in[2];         // (4,1024)
  Ws* ws = (Ws*)d_ws;
  float* out = (float*)d_out;

  stats_reduce<<<NROW / 256, 256, 0, stream>>>(targets, mask, ws);
  prep_kernel<<<1, 256, 0, stream>>>(outputs, ws);
  dist_fused<<<NSLOT / 4, 256, 0, stream>>>(outputs, targets, mask, ws);
  finalize_kernel<<<1, 256, 0, stream>>>(ws, out);
}